// Round 1
// baseline (814.724 us; speedup 1.0000x reference)
//
#include <hip/hip_runtime.h>
#include <cstdint>
#include <cmath>

// Problem constants (from reference): N=131072, M=64, K=8.
#define N_TOT 131072
#define NBLK  1024               // blocks in main kernel
#define WPB   4                  // waves per block (256 threads)
#define ITERS (N_TOT / (NBLK * WPB))   // 32 n per wave, exact

// One wave per n. Lane = (k,l): k=lane>>3, l=lane&7 (K=8 -> 64 pairs).
// Stage the n-slice (4 arrays x 512 floats = 8 KB) in wave-private LDS,
// compute re/im of h_k^T v_l over m=0..63, then SINR/log2 on diagonal lanes.
__global__ __launch_bounds__(256, 4)
void srl_main(const float* __restrict__ Hr, const float* __restrict__ Hi,
              const float* __restrict__ Vr, const float* __restrict__ Vi,
              const float* __restrict__ noise_p, float* __restrict__ partials) {
  __shared__ float buf[WPB][4][512];   // 32 KB: [wave][array][m*8+k]
  __shared__ float red[WPB];

  const int tid  = threadIdx.x;
  const int w    = tid >> 6;
  const int lane = tid & 63;
  const int k    = lane >> 3;
  const int l    = lane & 7;
  const float noise = noise_p[0];

  float* b0 = buf[w][0];  // Hr
  float* b1 = buf[w][1];  // Hi
  float* b2 = buf[w][2];  // Vr
  float* b3 = buf[w][3];  // Vi

  float acc = 0.f;
  const int n0 = blockIdx.x * (ITERS * WPB) + w;

  for (int it = 0; it < ITERS; ++it) {
    const size_t base = (size_t)(n0 + it * WPB) * 512;
    const float4* gh_r = (const float4*)(Hr + base);
    const float4* gh_i = (const float4*)(Hi + base);
    const float4* gv_r = (const float4*)(Vr + base);
    const float4* gv_i = (const float4*)(Vi + base);

    // Coalesced staging: 2 float4 per lane per array (1 KB per instruction).
    ((float4*)b0)[lane]      = gh_r[lane];
    ((float4*)b0)[64 + lane] = gh_r[64 + lane];
    ((float4*)b1)[lane]      = gh_i[lane];
    ((float4*)b1)[64 + lane] = gh_i[64 + lane];
    ((float4*)b2)[lane]      = gv_r[lane];
    ((float4*)b2)[64 + lane] = gv_r[64 + lane];
    ((float4*)b3)[lane]      = gv_i[lane];
    ((float4*)b3)[64 + lane] = gv_i[64 + lane];
    // Wave-private LDS: drain writes before reads (no block-wide barrier
    // needed, keeps the 4 waves decoupled for latency hiding).
    asm volatile("s_waitcnt lgkmcnt(0)" ::: "memory");

    // Split even/odd m accumulators to halve the FMA dependency chain.
    float re0 = 0.f, im0 = 0.f, re1 = 0.f, im1 = 0.f;
#pragma unroll
    for (int m = 0; m < 64; m += 2) {
      const float hr0 = b0[m * 8 + k];
      const float hi0 = b1[m * 8 + k];
      const float vr0 = b2[m * 8 + l];
      const float vi0 = b3[m * 8 + l];
      const float hr1 = b0[(m + 1) * 8 + k];
      const float hi1 = b1[(m + 1) * 8 + k];
      const float vr1 = b2[(m + 1) * 8 + l];
      const float vi1 = b3[(m + 1) * 8 + l];
      re0 = fmaf(hr0, vr0, re0); re0 = fmaf(-hi0, vi0, re0);
      im0 = fmaf(hr0, vi0, im0); im0 = fmaf(hi0, vr0, im0);
      re1 = fmaf(hr1, vr1, re1); re1 = fmaf(-hi1, vi1, re1);
      im1 = fmaf(hr1, vi1, im1); im1 = fmaf(hi1, vr1, im1);
    }
    // Reads drained before next iteration's staging overwrites the buffer.
    asm volatile("s_waitcnt lgkmcnt(0)" ::: "memory");

    const float re  = re0 + re1;
    const float im  = im0 + im1;
    const float nrm = fmaf(re, re, im * im);   // |h_k^T v_l|^2

    // Row-sum over l within the 8-lane k-group (xor of low-3 lane bits).
    float s = nrm;
    s += __shfl_xor(s, 1);
    s += __shfl_xor(s, 2);
    s += __shfl_xor(s, 4);

    if (l == k) {   // diagonal lane holds nom = nrm for its k
      const float denom = (s - nrm) + noise;
      acc += log2f(1.f + nrm / denom);
    }
    asm volatile("s_waitcnt lgkmcnt(0)" ::: "memory");
  }

  // Wave reduce (only diag lanes are nonzero), then block reduce.
#pragma unroll
  for (int off = 1; off < 64; off <<= 1) acc += __shfl_xor(acc, off);
  if (lane == 0) red[w] = acc;
  __syncthreads();
  if (tid == 0) partials[blockIdx.x] = red[0] + red[1] + red[2] + red[3];
}

__global__ __launch_bounds__(256)
void srl_finalize(const float* __restrict__ partials, float* __restrict__ out) {
  const int tid = threadIdx.x;
  float a = 0.f;
#pragma unroll
  for (int i = 0; i < NBLK / 256; ++i) a += partials[tid + i * 256];
#pragma unroll
  for (int off = 1; off < 64; off <<= 1) a += __shfl_xor(a, off);
  __shared__ float r[4];
  if ((tid & 63) == 0) r[tid >> 6] = a;
  __syncthreads();
  if (tid == 0) out[0] = -(r[0] + r[1] + r[2] + r[3]) * (1.f / (float)N_TOT);
}

extern "C" void kernel_launch(void* const* d_in, const int* in_sizes, int n_in,
                              void* d_out, int out_size, void* d_ws, size_t ws_size,
                              hipStream_t stream) {
  const float* Hr = (const float*)d_in[0];
  const float* Hi = (const float*)d_in[1];
  const float* Vr = (const float*)d_in[2];
  const float* Vi = (const float*)d_in[3];
  const float* nz = (const float*)d_in[4];
  float* out      = (float*)d_out;
  float* partials = (float*)d_ws;   // NBLK floats of scratch

  srl_main<<<NBLK, 256, 0, stream>>>(Hr, Hi, Vr, Vi, nz, partials);
  srl_finalize<<<1, 256, 0, stream>>>(partials, out);
}